// Round 1
// 110581.958 us; speedup vs baseline: 1.0894x; 1.0894x over previous
//
#include <hip/hip_runtime.h>

#define Bq 32
#define Sq 2048
#define Iq 128
#define Hq 512
#define Oq 128
#define NWG 256
#define NT 256
#define KB 256
#define SSTRIDE (KB + 4)  // dword stride per b-row in LDS; 260%32==4 -> b128 reads 2-way (free) under 16-lane phasing

__device__ __forceinline__ float sigmoidf_(float v) {
    return 1.0f / (1.0f + __expf(-v));
}

// Coherent-at-LLC data access (sc0 sc1), NO cache-maintenance fences.
__device__ __forceinline__ float ld_coh(const float* p) {
    return __hip_atomic_load(p, __ATOMIC_RELAXED, __HIP_MEMORY_SCOPE_AGENT);
}
__device__ __forceinline__ void st_coh(float* p, float v) {
    __hip_atomic_store(p, v, __ATOMIC_RELAXED, __HIP_MEMORY_SCOPE_AGENT);
}

// Fence-free flag barrier: each block stores epoch to its own flag (no
// atomics, no resets, flags are monotone). Block 0's 256 threads each watch
// one flag, then thread 0 publishes gen; other blocks' thread 0 polls gen.
// Each wave's pending stores drain at the __syncthreads s_barrier (compiler
// emits s_waitcnt vmcnt(0) before s_barrier), so by the time thread 0 stores
// the flag, the whole block's coherent stores are at the LLC.
// Flags live at bar[2*bid] (bid 0..255 -> ints 0..510); gen at bar[768].
// All within the 1024-int region bar_init zeroes.
__device__ __forceinline__ void gridbar(int* bar, int target) {
    __syncthreads();
    if (threadIdx.x == 0) {
        asm volatile("s_waitcnt vmcnt(0) lgkmcnt(0)" ::: "memory");
        __hip_atomic_store(bar + (blockIdx.x << 1), target, __ATOMIC_RELAXED,
                           __HIP_MEMORY_SCOPE_AGENT);
    }
    int* gen = bar + 768;
    if (blockIdx.x == 0) {
        // thread i watches block i's flag (NWG == NT == 256)
        while (__hip_atomic_load(bar + (threadIdx.x << 1), __ATOMIC_RELAXED,
                                 __HIP_MEMORY_SCOPE_AGENT) < target) {
            __builtin_amdgcn_s_sleep(1);
        }
        __syncthreads();
        if (threadIdx.x == 0) {
            __hip_atomic_store(gen, target, __ATOMIC_RELAXED,
                               __HIP_MEMORY_SCOPE_AGENT);
        }
    } else if (threadIdx.x == 0) {
        while (__hip_atomic_load(gen, __ATOMIC_RELAXED,
                                 __HIP_MEMORY_SCOPE_AGENT) < target) {
            __builtin_amdgcn_s_sleep(1);
        }
    }
    __syncthreads();
}

// Stage 32 x 256 chunk of mutable ws state (coherent loads) into sst[b][k].
// COALESCED: thread tid stages row u, column tid -> each wave instruction
// reads 64 consecutive dwords (1 sector-run) instead of 32 rows 2KB apart.
__device__ __forceinline__ void stage256(float* sst, const float* g,
                                         long rowStride, int k0) {
    __syncthreads();
    const int tid = threadIdx.x;
    const float* p = g + k0 + tid;
    float v[32];
#pragma unroll
    for (int u = 0; u < 32; ++u) v[u] = ld_coh(p + (long)u * rowStride);
#pragma unroll
    for (int u = 0; u < 32; ++u) sst[u * SSTRIDE + tid] = v[u];
    __syncthreads();
}

// Stage 32 x 128 chunk of IMMUTABLE input x (plain cached loads), coalesced:
// per wave, 2 rows x 32 float4 = two contiguous 512B runs.
__device__ __forceinline__ void stage128p(float* sst, const float* g,
                                          long rowStride) {
    __syncthreads();
    const int tid = threadIdx.x;
    const int k4 = tid & 31, bb = tid >> 5;
#pragma unroll
    for (int u = 0; u < 4; ++u) {
        int b = bb + (u << 3);
        float4 v = *(const float4*)(g + (long)b * rowStride + (k4 << 2));
        *(float4*)(sst + b * SSTRIDE + (k4 << 2)) = v;
    }
    __syncthreads();
}

// dot of weight row (plain cached, wave-broadcast) vs staged column b.
__device__ __forceinline__ float dotC(const float* sst,
                                      const float* __restrict__ Wrow, int b,
                                      int K) {
    const float* s = sst + b * SSTRIDE;
    float a0 = 0.f, a1 = 0.f, a2 = 0.f, a3 = 0.f;
#pragma unroll 8
    for (int k = 0; k < K; k += 4) {
        float4 w = *(const float4*)(Wrow + k);
        float4 h = *(const float4*)(s + k);  // ds_read_b128
        a0 = fmaf(w.x, h.x, a0);
        a1 = fmaf(w.y, h.y, a1);
        a2 = fmaf(w.z, h.z, a2);
        a3 = fmaf(w.w, h.w, a3);
    }
    return (a0 + a1) + (a2 + a3);
}

__global__ void bar_init(int* bar) {
    for (int i = threadIdx.x; i < 1024; i += 256) bar[i] = 0;
}

__global__ __launch_bounds__(NT, 1) void gru_fused(
    const float* __restrict__ x, const float* __restrict__ h0in,
    const float* __restrict__ Wx0, const float* __restrict__ Wh0,
    const float* __restrict__ bh0, const float* __restrict__ Wx1,
    const float* __restrict__ Wh1, const float* __restrict__ bh1,
    const float* __restrict__ Why, const float* __restrict__ bhy,
    float* __restrict__ out, float* __restrict__ ws) {
    __shared__ float sst[32 * SSTRIDE];  // 33.3 KB
    const int wg = blockIdx.x;
    const int tid = threadIdx.x;
    int* bar = (int*)(ws + 180224);
    int ep = 0;

    // workspace layout (floats) — all cross-block data, coherent access only
    float* h0 = ws;             // [b*512+j]
    float* h1 = ws + 16384;
    float* xzr0 = ws + 32768;   // [b*1024+j]
    float* xg0 = ws + 65536;    // [b*512+j]  (reused as xg1 in phases C/D)
    float* z0 = ws + 81920;
    float* rh0 = ws + 98304;
    float* hzr1 = ws + 114688;  // [b*1024+j]
    float* z1 = ws + 147456;
    float* rh1 = ws + 163840;
    float* xg1 = xg0;           // alias: xg0 dead after B, xg1 live C->D

    // ---- pre-loop ----
    if (wg < 86) {
        for (int i = wg * NT + tid; i < 2 * Bq * Hq; i += 86 * NT) {
            int b = i >> 10, l = (i >> 9) & 1, j = i & 511;
            st_coh((l ? h1 : h0) + b * Hq + j, h0in[i]);
        }
    } else {
        stage128p(sst, x, (long)Sq * Iq);  // x_0
        int lid = (wg - 86) * NT + tid;
        if (lid < Bq * 2 * Hq) {
            int b = lid & 31, j = lid >> 5;
            st_coh(xzr0 + b * 1024 + j, dotC(sst, Wx0 + j * Iq, b, Iq));
        }
    }
    gridbar(bar, ++ep);

    for (int t = 0;; ++t) {
        // ---- phase A (epilogue at t==S) ----
        if (t == Sq) {
            if (wg < 128) {
                int i = wg * NT + tid;  // 32768 = B*L*H
                int b = i >> 10, l = (i >> 9) & 1, j = i & 511;
                out[(size_t)Bq * Sq * Oq + i] = ld_coh((l ? h1 : h0) + b * Hq + j);
            } else if (wg >= 240) {
                int lid = (wg - 240) * NT + tid;  // 4096 = B*O
                int b = lid & 31, o = lid >> 5;
                float acc = 0.f;
                for (int kb = 0; kb < Hq; kb += KB) {
                    stage256(sst, h1, Hq, kb);
                    acc += dotC(sst, Why + o * Hq + kb, b, KB);
                }
                out[((size_t)b * Sq + (Sq - 1)) * Oq + o] = acc + bhy[o];
            }
            break;
        }
        if (wg < 160) {
            // A1: z0, r0, rh0
            int lid = wg * NT + tid;
            bool act = lid < Bq * 2 * Hq;
            int b = lid & 31, j = lid >> 5;
            float acc = 0.f;
            for (int kb = 0; kb < Hq; kb += KB) {
                stage256(sst, h0, Hq, kb);
                if (act) acc += dotC(sst, Wh0 + j * Hq + kb, b, KB);
            }
            if (act) {
                float s = sigmoidf_(ld_coh(xzr0 + b * 1024 + j) + acc + bh0[j]);
                if (j < Hq)
                    st_coh(z0 + b * Hq + j, s);
                else
                    st_coh(rh0 + b * Hq + (j - Hq),
                           s * ld_coh(h0 + b * Hq + (j - Hq)));
            }
        } else if (wg < 240) {
            // A2: xg0 = x_t @ Wx0_g^T
            stage128p(sst, x + (long)t * Iq, (long)Sq * Iq);
            int lid = (wg - 160) * NT + tid;
            if (lid < Bq * Hq) {
                int b = lid & 31, j = lid >> 5;
                st_coh(xg0 + b * Hq + j,
                       dotC(sst, Wx0 + (2 * Hq + j) * Iq, b, Iq));
            }
        } else {
            // A3: y_{t-1}
            int lid = (wg - 240) * NT + tid;
            int b = lid & 31, o = lid >> 5;
            float acc = 0.f;
            for (int kb = 0; kb < Hq; kb += KB) {
                stage256(sst, h1, Hq, kb);
                acc += dotC(sst, Why + o * Hq + kb, b, KB);
            }
            if (t > 0)
                out[((size_t)b * Sq + (t - 1)) * Oq + o] = acc + bhy[o];
        }
        gridbar(bar, ++ep);

        // ---- phase B ----
        if (wg < 86) {
            // B1: g0, h0 update
            int lid = wg * NT + tid;
            bool act = lid < Bq * Hq;
            int b = lid & 31, j = lid >> 5;
            float acc = 0.f;
            for (int kb = 0; kb < Hq; kb += KB) {
                stage256(sst, rh0, Hq, kb);
                if (act) acc += dotC(sst, Wh0 + (2 * Hq + j) * Hq + kb, b, KB);
            }
            if (act) {
                float g = tanhf(ld_coh(xg0 + b * Hq + j) + acc + bh0[2 * Hq + j]);
                float zz = ld_coh(z0 + b * Hq + j);
                float hold = ld_coh(h0 + b * Hq + j);
                st_coh(h0 + b * Hq + j, zz * hold + (1.f - zz) * g);
            }
        } else {
            // B2: hzr1 = h1 @ Wh1_zr^T + bh1_zr
            int lid = (wg - 86) * NT + tid;
            bool act = lid < Bq * 2 * Hq;
            int b = lid & 31, j = lid >> 5;
            float acc = 0.f;
            for (int kb = 0; kb < Hq; kb += KB) {
                stage256(sst, h1, Hq, kb);
                if (act) acc += dotC(sst, Wh1 + j * Hq + kb, b, KB);
            }
            if (act) st_coh(hzr1 + b * 1024 + j, acc + bh1[j]);
        }
        gridbar(bar, ++ep);

        // ---- phase C: consume updated h0 (= s0) ----
        {
            bool isC1 = wg < 170;
            int lid = isC1 ? wg * NT + tid : (wg - 170) * NT + tid;
            int nout = isC1 ? Bq * 2 * Hq : Bq * Hq;
            bool act = lid < nout;
            int b = lid & 31, j = lid >> 5;
            const float* Wrow =
                isC1 ? (Wx1 + j * Hq) : (Wx1 + (2 * Hq + j) * Hq);
            float acc = 0.f;
            for (int kb = 0; kb < Hq; kb += KB) {
                stage256(sst, h0, Hq, kb);
                if (act) acc += dotC(sst, Wrow + kb, b, KB);
            }
            if (act) {
                if (isC1) {
                    float s = sigmoidf_(acc + ld_coh(hzr1 + b * 1024 + j));
                    if (j < Hq)
                        st_coh(z1 + b * Hq + j, s);
                    else
                        st_coh(rh1 + b * Hq + (j - Hq),
                               s * ld_coh(h1 + b * Hq + (j - Hq)));
                } else {
                    st_coh(xg1 + b * Hq + j, acc);
                }
            }
        }
        gridbar(bar, ++ep);

        // ---- phase D ----
        if (wg < 86) {
            // D1: g1, h1 update
            int lid = wg * NT + tid;
            bool act = lid < Bq * Hq;
            int b = lid & 31, j = lid >> 5;
            float acc = 0.f;
            for (int kb = 0; kb < Hq; kb += KB) {
                stage256(sst, rh1, Hq, kb);
                if (act) acc += dotC(sst, Wh1 + (2 * Hq + j) * Hq + kb, b, KB);
            }
            if (act) {
                float g = tanhf(ld_coh(xg1 + b * Hq + j) + acc + bh1[2 * Hq + j]);
                float zz = ld_coh(z1 + b * Hq + j);
                float hold = ld_coh(h1 + b * Hq + j);
                st_coh(h1 + b * Hq + j, zz * hold + (1.f - zz) * g);
            }
        } else if (t + 1 < Sq) {
            // D2: xzr0 for t+1
            stage128p(sst, x + (long)(t + 1) * Iq, (long)Sq * Iq);
            int lid = (wg - 86) * NT + tid;
            if (lid < Bq * 2 * Hq) {
                int b = lid & 31, j = lid >> 5;
                st_coh(xzr0 + b * 1024 + j, dotC(sst, Wx0 + j * Iq, b, Iq));
            }
        }
        gridbar(bar, ++ep);
    }
}

extern "C" void kernel_launch(void* const* d_in, const int* in_sizes, int n_in,
                              void* d_out, int out_size, void* d_ws,
                              size_t ws_size, hipStream_t stream) {
    const float* x = (const float*)d_in[0];
    const float* h0in = (const float*)d_in[1];
    const float* Wx0 = (const float*)d_in[2];
    const float* Wh0 = (const float*)d_in[3];
    const float* bh0 = (const float*)d_in[4];
    const float* Wx1 = (const float*)d_in[5];
    const float* Wh1 = (const float*)d_in[6];
    const float* bh1 = (const float*)d_in[7];
    const float* Why = (const float*)d_in[8];
    const float* bhy = (const float*)d_in[9];
    float* out = (float*)d_out;
    float* ws = (float*)d_ws;
    int* bar = (int*)(ws + 180224);

    bar_init<<<1, 256, 0, stream>>>(bar);
    gru_fused<<<dim3(NWG), dim3(NT), 0, stream>>>(x, h0in, Wx0, Wh0, bh0, Wx1,
                                                  Wh1, bh1, Why, bhy, out, ws);
}

// Round 2
// 66870.563 us; speedup vs baseline: 1.8015x; 1.6537x over previous
//
#include <hip/hip_runtime.h>

#define Bq 32
#define Sq 2048
#define Iq 128
#define Hq 512
#define Oq 128
#define NWG 256
#define NT 256
#define KB 256
#define SSTRIDE (KB + 4)  // dword stride per b-row in LDS; 260%32==4 -> b128 reads 2-way (free) under 16-lane phasing

__device__ __forceinline__ float sigmoidf_(float v) {
    return 1.0f / (1.0f + __expf(-v));
}

// Coherent-at-LLC data access, NO cache-maintenance fences.
__device__ __forceinline__ float ld_coh(const float* p) {
    return __hip_atomic_load(p, __ATOMIC_RELAXED, __HIP_MEMORY_SCOPE_AGENT);
}
__device__ __forceinline__ void st_coh(float* p, float v) {
    __hip_atomic_store(p, v, __ATOMIC_RELAXED, __HIP_MEMORY_SCOPE_AGENT);
}

// Fence-free flag barrier: each block stores epoch to its own flag (no
// atomics, no resets, flags are monotone). Block 0's 256 threads each watch
// one flag, then thread 0 publishes gen; other blocks' thread 0 polls gen.
// Pending stores drain via explicit vmcnt(0) before the flag store.
// Flags live at bar[2*bid]; gen at bar[768]. All within the 1024-int region.
__device__ __forceinline__ void gridbar(int* bar, int target) {
    __syncthreads();
    if (threadIdx.x == 0) {
        asm volatile("s_waitcnt vmcnt(0) lgkmcnt(0)" ::: "memory");
        __hip_atomic_store(bar + (blockIdx.x << 1), target, __ATOMIC_RELAXED,
                           __HIP_MEMORY_SCOPE_AGENT);
    }
    int* gen = bar + 768;
    if (blockIdx.x == 0) {
        while (__hip_atomic_load(bar + (threadIdx.x << 1), __ATOMIC_RELAXED,
                                 __HIP_MEMORY_SCOPE_AGENT) < target) {
            __builtin_amdgcn_s_sleep(1);
        }
        __syncthreads();
        if (threadIdx.x == 0) {
            __hip_atomic_store(gen, target, __ATOMIC_RELAXED,
                               __HIP_MEMORY_SCOPE_AGENT);
        }
    } else if (threadIdx.x == 0) {
        while (__hip_atomic_load(gen, __ATOMIC_RELAXED,
                                 __HIP_MEMORY_SCOPE_AGENT) < target) {
            __builtin_amdgcn_s_sleep(1);
        }
    }
    __syncthreads();
}

// Stage 32 x 256 chunk of mutable ws state (coherent loads) into sst[b][k].
// COALESCED: thread tid stages row u, column tid -> each wave instruction
// reads 64 consecutive dwords.
__device__ __forceinline__ void stage256(float* sst, const float* g,
                                         long rowStride, int k0) {
    __syncthreads();
    const int tid = threadIdx.x;
    const float* p = g + k0 + tid;
    float v[32];
#pragma unroll
    for (int u = 0; u < 32; ++u) v[u] = ld_coh(p + (long)u * rowStride);
#pragma unroll
    for (int u = 0; u < 32; ++u) sst[u * SSTRIDE + tid] = v[u];
    __syncthreads();
}

// Stage 32 x 128 chunk of IMMUTABLE input x (plain cached loads), coalesced.
__device__ __forceinline__ void stage128p(float* sst, const float* g,
                                          long rowStride) {
    __syncthreads();
    const int tid = threadIdx.x;
    const int k4 = tid & 31, bb = tid >> 5;
#pragma unroll
    for (int u = 0; u < 4; ++u) {
        int b = bb + (u << 3);
        float4 v = *(const float4*)(g + (long)b * rowStride + (k4 << 2));
        *(float4*)(sst + b * SSTRIDE + (k4 << 2)) = v;
    }
    __syncthreads();
}

// dot of weight row (plain cached, wave-broadcast) vs staged column b.
__device__ __forceinline__ float dotC(const float* sst,
                                      const float* __restrict__ Wrow, int b,
                                      int K) {
    const float* s = sst + b * SSTRIDE;
    float a0 = 0.f, a1 = 0.f, a2 = 0.f, a3 = 0.f;
#pragma unroll 8
    for (int k = 0; k < K; k += 4) {
        float4 w = *(const float4*)(Wrow + k);
        float4 h = *(const float4*)(s + k);  // ds_read_b128
        a0 = fmaf(w.x, h.x, a0);
        a1 = fmaf(w.y, h.y, a1);
        a2 = fmaf(w.z, h.z, a2);
        a3 = fmaf(w.w, h.w, a3);
    }
    return (a0 + a1) + (a2 + a3);
}

__global__ void bar_init(int* bar) {
    for (int i = threadIdx.x; i < 1024; i += 256) bar[i] = 0;
}

// 2-tick-per-timestep pipelined schedule (layer 1 runs one step behind
// layer 0, sharing ticks):
//   E(t): A1(t) z0/rh0        [wg 0..127, stage h0]
//         C2(t-1) xg1         [wg 0..63, reuses staged h0]
//         C1(t-1) z1/rh1      [wg 128..255, stage h0 + h1, fused hzr1 dot]
//         Y(t-2)              [wg 240..255, reuses staged h1]
//   O(t): B1(t) h0 update     [wg 0..63, stage rh0]
//         D1(t-1) h1 update   [wg 64..127, stage rh1]
//         X(t+1) xzr0/xg0     [wg 128..223, stage x]
// xg0 is double-buffered (parity t) since X(t+1) and B1(t) share O(t).
__global__ __launch_bounds__(NT, 1) void gru_fused(
    const float* __restrict__ x, const float* __restrict__ h0in,
    const float* __restrict__ Wx0, const float* __restrict__ Wh0,
    const float* __restrict__ bh0, const float* __restrict__ Wx1,
    const float* __restrict__ Wh1, const float* __restrict__ bh1,
    const float* __restrict__ Why, const float* __restrict__ bhy,
    float* __restrict__ out, float* __restrict__ ws) {
    __shared__ float sst[32 * SSTRIDE];  // 33.3 KB
    const int wg = blockIdx.x;
    const int tid = threadIdx.x;
    int* bar = (int*)(ws + 180224);
    int ep = 0;

    // workspace layout (floats) — all cross-block data, coherent access only
    float* h0 = ws;              // [b*512+j]
    float* h1 = ws + 16384;
    float* xzr0 = ws + 32768;    // [b*1024+jj], jj<1024
    float* xg0 = ws + 65536;     // 2 x [b*512+j], parity t&1
    float* z0 = ws + 98304;
    float* rh0 = ws + 114688;
    float* z1 = ws + 131072;
    float* rh1 = ws + 147456;
    float* xg1 = ws + 163840;

    // ---- pre-tick: init h0/h1; X(0) into xzr0 + xg0[0] ----
    if (wg < 86) {
        for (int i = wg * NT + tid; i < 2 * Bq * Hq; i += 86 * NT) {
            int b = i >> 10, l = (i >> 9) & 1, j = i & 511;
            st_coh((l ? h1 : h0) + b * Hq + j, h0in[i]);
        }
    } else if (wg >= 128 && wg < 224) {
        stage128p(sst, x, (long)Sq * Iq);  // x_0
        int base = (wg - 128) * 512;
#pragma unroll
        for (int c = 0; c < 2; ++c) {
            int lid = base + c * NT + tid;
            int b = lid & 31, jj = lid >> 5;  // jj in [0,1536)
            float d = dotC(sst, Wx0 + jj * Iq, b, Iq);
            if (jj < 1024)
                st_coh(xzr0 + b * 1024 + jj, d);
            else
                st_coh(xg0 + b * Hq + (jj - 1024), d);  // parity 0
        }
    }
    gridbar(bar, ++ep);

    for (int t = 0; t <= Sq; ++t) {
        // ======== E tick ========
        if (wg < 128) {
            // stage h0(t-1); A1(t) + C2(t-1)
            int lid = wg * NT + tid;
            int b = lid & 31, j = lid >> 5;  // j in [0,1024)
            bool doA = (t < Sq);
            bool doC2 = (wg < 64) && (t >= 1);  // j < 512 for these blocks
            float accA = 0.f, accC = 0.f;
            for (int kb = 0; kb < Hq; kb += KB) {
                stage256(sst, h0, Hq, kb);
                if (doA) accA += dotC(sst, Wh0 + j * Hq + kb, b, KB);
                if (doC2) accC += dotC(sst, Wx1 + (2 * Hq + j) * Hq + kb, b, KB);
            }
            if (doA) {
                float s = sigmoidf_(ld_coh(xzr0 + b * 1024 + j) + accA + bh0[j]);
                if (j < Hq)
                    st_coh(z0 + b * Hq + j, s);
                else
                    st_coh(rh0 + b * Hq + (j - Hq),
                           s * ld_coh(h0 + b * Hq + (j - Hq)));
            }
            if (doC2) st_coh(xg1 + b * Hq + j, accC);
        } else {
            // stage h0(t-1) and h1(t-2); C1(t-1) fused (+Y(t-2) on 240..255)
            int lid = (wg - 128) * NT + tid;
            int b = lid & 31, j = lid >> 5;  // j in [0,1024)
            bool doC1 = (t >= 1);
            bool doY = (wg >= 240) && (t >= 2);
            int lidY = (wg - 240) * NT + tid;  // [0,4096)
            int bY = lidY & 31, oY = lidY >> 5;
            float acc1 = 0.f, acc2 = 0.f, accY = 0.f;
            for (int kb = 0; kb < Hq; kb += KB) {
                stage256(sst, h0, Hq, kb);
                if (doC1) acc1 += dotC(sst, Wx1 + j * Hq + kb, b, KB);
                stage256(sst, h1, Hq, kb);
                if (doC1) acc2 += dotC(sst, Wh1 + j * Hq + kb, b, KB);
                if (doY) accY += dotC(sst, Why + oY * Hq + kb, bY, KB);
            }
            if (doC1) {
                float s = sigmoidf_(acc1 + acc2 + bh1[j]);
                if (j < Hq)
                    st_coh(z1 + b * Hq + j, s);
                else
                    st_coh(rh1 + b * Hq + (j - Hq),
                           s * ld_coh(h1 + b * Hq + (j - Hq)));
            }
            if (doY) out[((size_t)bY * Sq + (t - 2)) * Oq + oY] = accY + bhy[oY];
        }
        gridbar(bar, ++ep);

        // ======== O tick ========
        if (wg < 64) {
            // B1(t): h0 update
            if (t < Sq) {
                int lid = wg * NT + tid;
                int b = lid & 31, j = lid >> 5;  // [0,512)
                float acc = 0.f;
                for (int kb = 0; kb < Hq; kb += KB) {
                    stage256(sst, rh0, Hq, kb);
                    acc += dotC(sst, Wh0 + (2 * Hq + j) * Hq + kb, b, KB);
                }
                float g = tanhf(ld_coh(xg0 + (t & 1) * 16384 + b * Hq + j) +
                                acc + bh0[2 * Hq + j]);
                float zz = ld_coh(z0 + b * Hq + j);
                float hold = ld_coh(h0 + b * Hq + j);
                st_coh(h0 + b * Hq + j, zz * hold + (1.f - zz) * g);
            }
        } else if (wg < 128) {
            // D1(t-1): h1 update
            if (t >= 1) {
                int lid = (wg - 64) * NT + tid;
                int b = lid & 31, j = lid >> 5;
                float acc = 0.f;
                for (int kb = 0; kb < Hq; kb += KB) {
                    stage256(sst, rh1, Hq, kb);
                    acc += dotC(sst, Wh1 + (2 * Hq + j) * Hq + kb, b, KB);
                }
                float g = tanhf(ld_coh(xg1 + b * Hq + j) + acc + bh1[2 * Hq + j]);
                float zz = ld_coh(z1 + b * Hq + j);
                float hold = ld_coh(h1 + b * Hq + j);
                st_coh(h1 + b * Hq + j, zz * hold + (1.f - zz) * g);
            }
        } else if (wg < 224) {
            // X(t+1): xzr0 and xg0[par] for next step
            if (t + 1 < Sq) {
                stage128p(sst, x + (long)(t + 1) * Iq, (long)Sq * Iq);
                int base = (wg - 128) * 512;
                int par = (t + 1) & 1;
#pragma unroll
                for (int c = 0; c < 2; ++c) {
                    int lid = base + c * NT + tid;
                    int b = lid & 31, jj = lid >> 5;
                    float d = dotC(sst, Wx0 + jj * Iq, b, Iq);
                    if (jj < 1024)
                        st_coh(xzr0 + b * 1024 + jj, d);
                    else
                        st_coh(xg0 + par * 16384 + b * Hq + (jj - 1024), d);
                }
            }
        }
        gridbar(bar, ++ep);
    }

    // ---- final tick: hidden state + Y(Sq-1) ----
    if (wg < 128) {
        int i = wg * NT + tid;  // 32768 = B*L*H
        int b = i >> 10, l = (i >> 9) & 1, j = i & 511;
        out[(size_t)Bq * Sq * Oq + i] = ld_coh((l ? h1 : h0) + b * Hq + j);
    } else if (wg >= 240) {
        int lid = (wg - 240) * NT + tid;  // 4096 = B*O
        int b = lid & 31, o = lid >> 5;
        float acc = 0.f;
        for (int kb = 0; kb < Hq; kb += KB) {
            stage256(sst, h1, Hq, kb);
            acc += dotC(sst, Why + o * Hq + kb, b, KB);
        }
        out[((size_t)b * Sq + (Sq - 1)) * Oq + o] = acc + bhy[o];
    }
}

extern "C" void kernel_launch(void* const* d_in, const int* in_sizes, int n_in,
                              void* d_out, int out_size, void* d_ws,
                              size_t ws_size, hipStream_t stream) {
    const float* x = (const float*)d_in[0];
    const float* h0in = (const float*)d_in[1];
    const float* Wx0 = (const float*)d_in[2];
    const float* Wh0 = (const float*)d_in[3];
    const float* bh0 = (const float*)d_in[4];
    const float* Wx1 = (const float*)d_in[5];
    const float* Wh1 = (const float*)d_in[6];
    const float* bh1 = (const float*)d_in[7];
    const float* Why = (const float*)d_in[8];
    const float* bhy = (const float*)d_in[9];
    float* out = (float*)d_out;
    float* ws = (float*)d_ws;
    int* bar = (int*)(ws + 180224);

    bar_init<<<1, 256, 0, stream>>>(bar);
    gru_fused<<<dim3(NWG), dim3(NT), 0, stream>>>(x, h0in, Wx0, Wh0, bh0, Wx1,
                                                  Wh1, bh1, Why, bhy, out, ws);
}